// Round 5
// baseline (192.668 us; speedup 1.0000x reference)
//
#include <hip/hip_runtime.h>
#include <stdint.h>

typedef uint32_t u32;
typedef uint64_t u64;

// BinaryNet on MI355X: everything after binarize() is {-1,0,+1}.
// Layer1 (9 taps, odd) -> exact +-1 per output -> 1 bit.
// Layer2 (36 taps, even) -> ternary -> (value bit, nonzero bit).
// All convs/FCs computed as XOR + popcount on packed sign bits.
//
// R10: per-lane independent staging (no ballot, no LDS, no barrier).
// R9's rocprof finally caught binnet directly: 102us, 7% HBM, 9% VALU,
// 22% occupancy, VGPR=76 -> latency-bound. The ballot staging couples all
// 64 lanes into one serial chain (convergent op + lane0 LDS store per word)
// and the compiler collapsed the 45-deep batch (76 VGPRs can't hold it):
// ~225 serial rounds x ~1000cy ~= the measured 102us. An L3-warm profiled
// dispatch (0.5MB fetched) still took 102us -> pure dependence chain.
//
// Fix: one lane = one sample. Each lane loads its own 225 floats as 57
// ALIGNED float4s (sample base gid*225 is 4B-aligned only; load from the
// rounded-down float4 base, assemble 228 sign bits, then shift right by
// off = (gid*225)&3). Worst-case coverage ends exactly at the buffer's last
// float (gid=131071: off=3) -> no OOB. Load consumers are plain per-lane
// VALU (no cross-lane dep), so the compiler pipelines the loads; all 57
// share one base with immediate offsets. 900B lane stride costs ~4x L1/L2
// transactions but every 64B line is fully consumed across 4 consecutive k
// -> HBM bytes unchanged. Bv[4] is bit-identical in meaning to the verified
// LDS-derived version; rb extraction, conv layers, FCs, and the R7
// ballot-gather weight packing are verbatim.
//
// Launch: <<<B/64, 64>>>, __launch_bounds__(64,2) -> 128-VGPR budget at the
// grid's natural 2 waves/SIMD; 8 independent 1-wave blocks/CU.
//
// Bit-layout reference:
//   w1p[c]  : 9-bit,  bit 3*ky+kx
//   W2[d]   : 36-bit, bit 12*ky+4*kx+c
//   W3L[e]  : 64-bit, bit 8*(3*ky+kx)+d  (taps 0..7)
//   W3H[e]  : 8-bit,  bit d              (tap 8)
//   WF1[j]  : 16-bit, bit e
//   wf2     : 8-bit,  bit j

__global__ __launch_bounds__(64, 2) void binnet(const float* __restrict__ x,
                                                const float* __restrict__ w1,
                                                const float* __restrict__ w2,
                                                const float* __restrict__ w3,
                                                const float* __restrict__ wfc1,
                                                const float* __restrict__ wfc2,
                                                float* __restrict__ out) {
  const int lane = threadIdx.x;            // one wave per block
  const int gid = blockIdx.x * 64 + lane;  // one lane = one sample
  const int f0 = gid * 225;                // fits i32 (max ~29.5M)
  const int q0 = f0 >> 2;                  // aligned float4 index
  const int off = f0 & 3;                  // 0..3 float phase
  const float4* xq = (const float4*)x + q0;

  // ---- Stage: 57 aligned float4 loads, sign bits into SW[0..3] ----
  // SW bit r = sign(float 4*q0 + r), r = 0..227. All shifts compile-time.
  u64 SW[4] = {0, 0, 0, 0};
  #pragma unroll
  for (int g = 0; g < 4; ++g) {
    float4 v[14];
    #pragma unroll
    for (int k = 0; k < 14; ++k) v[k] = xq[g * 14 + k];
    #pragma unroll
    for (int k = 0; k < 14; ++k) {
      const int rel = (g * 14 + k) * 4;
      SW[(rel    ) >> 6] |= (u64)(v[k].x < 0.f) << ((rel    ) & 63);
      SW[(rel + 1) >> 6] |= (u64)(v[k].y < 0.f) << ((rel + 1) & 63);
      SW[(rel + 2) >> 6] |= (u64)(v[k].z < 0.f) << ((rel + 2) & 63);
      SW[(rel + 3) >> 6] |= (u64)(v[k].w < 0.f) << ((rel + 3) & 63);
    }
  }
  {  // k = 56: floats rel 224..227 -> SW[3] bits 32..35
    const float4 v = xq[56];
    SW[3] |= (u64)(v.x < 0.f) << 32;
    SW[3] |= (u64)(v.y < 0.f) << 33;
    SW[3] |= (u64)(v.z < 0.f) << 34;
    SW[3] |= (u64)(v.w < 0.f) << 35;
  }

  // ---- Shift by off: Bv[i] bit j = sign(x[sample float 64i+j]) ----
  u64 Bv[4];
  Bv[0] = (SW[0] >> off) | ((SW[1] << (63 - off)) << 1);  // off==0 -> 0 contribution
  Bv[1] = (SW[1] >> off) | ((SW[2] << (63 - off)) << 1);
  Bv[2] = (SW[2] >> off) | ((SW[3] << (63 - off)) << 1);
  Bv[3] = (SW[3] >> off) & 0x1FFFFFFFFull;  // keep floats 192..224 only

  // rows: rb[r] bit k = sign(x[b,0,r,k])  (verbatim verified code)
  u32 rb[15];
  #pragma unroll
  for (int r = 0; r < 15; ++r) {
    const int f = 15 * r, w = f >> 6, o = f & 63;
    u64 v = Bv[w] >> o;
    if (o > 49) v |= Bv[w + 1] << (64 - o);
    rb[r] = (u32)v & 0x7FFFu;
  }

  // ---- Weight packing via inverse-permuted sign ballots (R7, verified) ----
  const float vw1 = w1[lane < 36 ? lane : 0];
  const u64 m1 = __ballot((lane < 36) && (vw1 < 0.f));
  const u32 w1p0 = (u32)(m1      ) & 0x1FFu;
  const u32 w1p1 = (u32)(m1 >>  9) & 0x1FFu;
  const u32 w1p2 = (u32)(m1 >> 18) & 0x1FFu;
  const u32 w1p3 = (u32)(m1 >> 27) & 0x1FFu;

  const int w2i = (lane < 36) ? ((lane & 3) * 9 + (lane >> 2)) : 0;
  u64 W2[8];
  #pragma unroll
  for (int d = 0; d < 8; ++d) {
    const float v = w2[d * 36 + w2i];
    W2[d] = __ballot((lane < 36) && (v < 0.f));   // bits >=36 are 0
  }

  const int w3i = (lane & 7) * 9 + (lane >> 3);
  u64 W3L[16];
  u32 W3H[16];
  #pragma unroll
  for (int e = 0; e < 16; ++e) W3L[e] = __ballot(w3[e * 72 + w3i] < 0.f);
  {
    const int hb = (lane & 7) * 9 + 8;
    const u64 h0 = __ballot(w3[((lane >> 3)    ) * 72 + hb] < 0.f);
    const u64 h1 = __ballot(w3[((lane >> 3) + 8) * 72 + hb] < 0.f);
    #pragma unroll
    for (int e = 0; e < 16; ++e)
      W3H[e] = (u32)(((e < 8 ? h0 : h1) >> (8 * (e & 7))) & 0xFFu);
  }

  const u64 f0b = __ballot(wfc1[lane] < 0.f);
  const u64 f1b = __ballot(wfc1[64 + lane] < 0.f);
  u32 WF1[8];
  #pragma unroll
  for (int j = 0; j < 8; ++j)
    WF1[j] = (u32)(((j < 4 ? f0b : f1b) >> (16 * (j & 3))) & 0xFFFFu);

  const float vf2 = wfc2[lane < 8 ? lane : 0];
  const u32 wf2 = (u32)__ballot((lane < 8) && (vf2 < 0.f)) & 0xFFu;

  // ---- Layer 1: 4ch, 15x15 -> 7x7, 9 taps (always +-1 out) ----
  u64 a1[4] = {0, 0, 0, 0};  // bit 4*(7*oy+ox)+c, 1 = negative
  int pix = 0;
  #pragma unroll
  for (int oy = 0; oy < 7; ++oy) {
    const u32 r0 = rb[2 * oy], r1 = rb[2 * oy + 1], r2 = rb[2 * oy + 2];
    #pragma unroll
    for (int ox = 0; ox < 7; ++ox) {
      const u32 t9 = ((r0 >> (2 * ox)) & 7) | (((r1 >> (2 * ox)) & 7) << 3)
                   | (((r2 >> (2 * ox)) & 7) << 6);
      u32 nib = 0;
      nib |= (u32)(__popc(t9 ^ w1p0) >= 5) << 0;
      nib |= (u32)(__popc(t9 ^ w1p1) >= 5) << 1;
      nib |= (u32)(__popc(t9 ^ w1p2) >= 5) << 2;
      nib |= (u32)(__popc(t9 ^ w1p3) >= 5) << 3;
      a1[pix >> 4] |= (u64)nib << ((pix & 15) * 4);
      ++pix;
    }
  }

  // ---- Layer 2: 8ch, 7x7 -> 3x3, 36 taps (ternary out) ----
  u64 v2lo = 0, nz2lo = 0; u32 v2hi = 0, nz2hi = 0;  // bit 8*(3*oy+ox)+d
  #pragma unroll
  for (int oy = 0; oy < 3; ++oy) {
    #pragma unroll
    for (int ox = 0; ox < 3; ++ox) {
      u64 T = 0;
      #pragma unroll
      for (int ky = 0; ky < 3; ++ky) {
        const int p = 4 * (7 * (2 * oy + ky) + 2 * ox);
        const int w = p >> 6, o = p & 63;
        u64 v = a1[w] >> o;
        if (o > 52) v |= a1[w + 1] << (64 - o);
        T |= (v & 0xFFFull) << (12 * ky);
      }
      const int pix2 = 3 * oy + ox;
      u32 bv = 0, bz = 0;
      #pragma unroll
      for (int d = 0; d < 8; ++d) {
        const int cnt = __popcll(T ^ W2[d]);  // #neg products of 36
        bv |= (u32)(cnt > 18) << d;           // sum = 36-2cnt < 0
        bz |= (u32)(cnt != 18) << d;          // nonzero
      }
      if (pix2 < 8) { v2lo |= (u64)bv << (8 * pix2); nz2lo |= (u64)bz << (8 * pix2); }
      else          { v2hi = bv; nz2hi = bz; }
    }
  }

  // ---- Layer 3: 16ch, 3x3 -> 1x1, 72 taps, ternary in/out ----
  const int nztot = __popcll(nz2lo) + __popc(nz2hi);
  u32 s3v = 0, s3nz = 0;
  #pragma unroll
  for (int e = 0; e < 16; ++e) {
    const int cnt = __popcll(nz2lo & (v2lo ^ W3L[e])) + __popc(nz2hi & (v2hi ^ W3H[e]));
    const int s = nztot - 2 * cnt;
    s3v  |= (u32)(s < 0) << e;
    s3nz |= (u32)(s != 0) << e;
  }

  // ---- FC1: 16 -> 8, ternary ----
  const int n3 = __popc(s3nz);
  u32 hv = 0, hz = 0;
  #pragma unroll
  for (int j = 0; j < 8; ++j) {
    const int c2 = __popc(s3nz & (s3v ^ WF1[j]));
    const int s = n3 - 2 * c2;
    hv |= (u32)(s < 0) << j;
    hz |= (u32)(s != 0) << j;
  }

  // ---- FC2: 8 -> 1 (no hardtanh) ----
  const int c3 = __popc(hz & (hv ^ wf2));
  const int sfin = __popc(hz) - 2 * c3;
  out[gid] = (float)sfin;
}

extern "C" void kernel_launch(void* const* d_in, const int* in_sizes, int n_in,
                              void* d_out, int out_size, void* d_ws, size_t ws_size,
                              hipStream_t stream) {
  const float* x    = (const float*)d_in[0];
  const float* w1   = (const float*)d_in[1];
  const float* w2   = (const float*)d_in[2];
  const float* w3   = (const float*)d_in[3];
  const float* wfc1 = (const float*)d_in[4];
  const float* wfc2 = (const float*)d_in[5];
  float* out = (float*)d_out;
  const int B = in_sizes[0] / 225;  // 131072

  (void)d_ws; (void)ws_size; (void)n_in; (void)out_size;
  binnet<<<B / 64, 64, 0, stream>>>(x, w1, w2, w3, wfc1, wfc2, out);
}

// Round 6
// 185.539 us; speedup vs baseline: 1.0384x; 1.0384x over previous
//
#include <hip/hip_runtime.h>
#include <stdint.h>

typedef uint32_t u32;
typedef uint64_t u64;

// BinaryNet on MI355X: everything after binarize() is {-1,0,+1}.
// Layer1 (9 taps, odd) -> exact +-1 per output -> 1 bit.
// Layer2 (36 taps, even) -> ternary -> (value bit, nonzero bit).
// All convs/FCs computed as XOR + popcount on packed sign bits.
//
// FINAL (R11) = the twice-verified best kernel (R7/R9: 185.6 / 185.4 us).
// Session evidence (6 variants, 3 orthogonal structural attacks):
//  - R6  1-wave blocks, 4x blocks:        190.0  (null -> not phase-bound)
//  - R8  float4 staging, 4x fewer rounds: 187.6  (null -> not chain-depth-bound)
//  - R10 per-lane, no ballot/LDS/barrier: 192.7  (small L2-thrash regression)
// All variants within +-4 us of 188 -> total is insensitive to binnet
// structure. The timed window is dominated by harness-owned work: one 450 MiB
// ws-poison fill (~68 us @ 87% HBM) + ~35-40 small reset dispatches/iter
// (~70-90 us of launch overhead). binnet contributes ~30-50 us vs its
// 18.7 us mandatory-read floor (118 MB of f32 signs, read once). This is
// the controllable roofline.
//
// Single-kernel design: weight packing via inverse-permuted ballot-gather
// (each lane loads the weight element whose TARGET bit position equals its
// lane index; one __ballot per packed word), placed AFTER the x-staging loop
// so the 45-deep load batch (~56 live VGPRs) and the ~87 weight VGPRs are
// never simultaneously live. Launch: <<<B/64, 64>>>, __launch_bounds__(64,2)
// -> full 128-VGPR budget at 2 waves/SIMD; 8 independent 1-wave blocks/CU.
//
// Bit-layout reference:
//   w1p[c]  : 9-bit,  bit 3*ky+kx
//   W2[d]   : 36-bit, bit 12*ky+4*kx+c
//   W3L[e]  : 64-bit, bit 8*(3*ky+kx)+d  (taps 0..7)
//   W3H[e]  : 8-bit,  bit d              (tap 8)
//   WF1[j]  : 16-bit, bit e
//   wf2     : 8-bit,  bit j

__global__ __launch_bounds__(64, 2) void binnet(const float* __restrict__ x,
                                                const float* __restrict__ w1,
                                                const float* __restrict__ w2,
                                                const float* __restrict__ w3,
                                                const float* __restrict__ wfc1,
                                                const float* __restrict__ wfc2,
                                                float* __restrict__ out) {
  __shared__ u64 st[228];
  const int lane = threadIdx.x;       // one wave per block
  const int b0 = blockIdx.x * 64;     // this block's 64 samples

  // ---- Stage this wave's 64 samples' 225 sign words (flat float order) ----
  // word t = ballot over lanes of float [b0*225 + 64t + lane].
  // 5 groups of 45: all 45 coalesced loads issue before the ballot/store
  // drain (45 live floats ~ 55 VGPRs).
  const float* xw = x + (size_t)b0 * 225 + lane;
  if (lane < 3) st[225 + lane] = 0;   // zero tail words
  #pragma unroll
  for (int g = 0; g < 5; ++g) {
    float v[45];
    #pragma unroll
    for (int k = 0; k < 45; ++k) v[k] = xw[(g * 45 + k) * 64];
    #pragma unroll
    for (int k = 0; k < 45; ++k) {
      const u64 m = __ballot(v[k] < 0.f);
      if (lane == 0) st[g * 45 + k] = m;
    }
  }

  // ---- Weight packing via inverse-permuted sign ballots ----
  // w1 [4][9]: memory order c*9+k == bit order 9c+k. One ballot.
  const float vw1 = w1[lane < 36 ? lane : 0];
  const u64 m1 = __ballot((lane < 36) && (vw1 < 0.f));
  const u32 w1p0 = (u32)(m1      ) & 0x1FFu;
  const u32 w1p1 = (u32)(m1 >>  9) & 0x1FFu;
  const u32 w1p2 = (u32)(m1 >> 18) & 0x1FFu;
  const u32 w1p3 = (u32)(m1 >> 27) & 0x1FFu;

  // w2 [8][4][3][3]: target bit bp = 4t+c (t=3ky+kx) <- mem d*36 + c*9 + t.
  // Lane bp loads (bp&3)*9 + (bp>>2); lanes >=36 clamped + predicated off.
  const int w2i = (lane < 36) ? ((lane & 3) * 9 + (lane >> 2)) : 0;
  u64 W2[8];
  #pragma unroll
  for (int d = 0; d < 8; ++d) {
    const float v = w2[d * 36 + w2i];
    W2[d] = __ballot((lane < 36) && (v < 0.f));   // bits >=36 are 0
  }

  // w3 [16][8][3][3]: target bit bp = 8t+d <- mem e*72 + d*9 + t.
  // Lo (t=0..7): lane l loads e*72 + (l&7)*9 + (l>>3)  -> bit l = 8t+d.
  // Hi (t=8): two combined ballots, 8 channels' bit-d bytes per ballot.
  const int w3i = (lane & 7) * 9 + (lane >> 3);
  u64 W3L[16];
  u32 W3H[16];
  #pragma unroll
  for (int e = 0; e < 16; ++e) W3L[e] = __ballot(w3[e * 72 + w3i] < 0.f);
  {
    const int hb = (lane & 7) * 9 + 8;
    const u64 h0 = __ballot(w3[((lane >> 3)    ) * 72 + hb] < 0.f);
    const u64 h1 = __ballot(w3[((lane >> 3) + 8) * 72 + hb] < 0.f);
    #pragma unroll
    for (int e = 0; e < 16; ++e)
      W3H[e] = (u32)(((e < 8 ? h0 : h1) >> (8 * (e & 7))) & 0xFFu);
  }

  // wfc1 [8][16]: memory order j*16+e == bit order. Two ballots.
  const u64 f0 = __ballot(wfc1[lane] < 0.f);
  const u64 f1 = __ballot(wfc1[64 + lane] < 0.f);
  u32 WF1[8];
  #pragma unroll
  for (int j = 0; j < 8; ++j)
    WF1[j] = (u32)(((j < 4 ? f0 : f1) >> (16 * (j & 3))) & 0xFFFFu);

  // wfc2 [1][8]
  const float vf2 = wfc2[lane < 8 ? lane : 0];
  const u32 wf2 = (u32)__ballot((lane < 8) && (vf2 < 0.f)) & 0xFFu;

  __syncthreads();  // single-wave barrier: orders LDS ballot-stores -> reads

  // ---- Eval: byte-identical to the verified R3/R4 kernel ----
  const u64* stw = st;
  const int f0i = 225 * lane;
  const int w0 = f0i >> 6;
  const int sh = f0i & 63;
  u64 Wd[5];
  #pragma unroll
  for (int i = 0; i < 5; ++i) Wd[i] = stw[w0 + i];
  u64 Bv[4];
  #pragma unroll
  for (int i = 0; i < 4; ++i)
    Bv[i] = (Wd[i] >> sh) | ((Wd[i + 1] << (63 - sh)) << 1);  // sh==0 -> 0 contribution

  // rows: rb[r] bit k = sign(x[b,0,r,k])
  u32 rb[15];
  #pragma unroll
  for (int r = 0; r < 15; ++r) {
    const int f = 15 * r, w = f >> 6, o = f & 63;
    u64 v = Bv[w] >> o;
    if (o > 49) v |= Bv[w + 1] << (64 - o);
    rb[r] = (u32)v & 0x7FFFu;
  }

  // ---- Layer 1: 4ch, 15x15 -> 7x7, 9 taps (always +-1 out) ----
  u64 a1[4] = {0, 0, 0, 0};  // bit 4*(7*oy+ox)+c, 1 = negative
  int pix = 0;
  #pragma unroll
  for (int oy = 0; oy < 7; ++oy) {
    const u32 r0 = rb[2 * oy], r1 = rb[2 * oy + 1], r2 = rb[2 * oy + 2];
    #pragma unroll
    for (int ox = 0; ox < 7; ++ox) {
      const u32 t9 = ((r0 >> (2 * ox)) & 7) | (((r1 >> (2 * ox)) & 7) << 3)
                   | (((r2 >> (2 * ox)) & 7) << 6);
      u32 nib = 0;
      nib |= (u32)(__popc(t9 ^ w1p0) >= 5) << 0;
      nib |= (u32)(__popc(t9 ^ w1p1) >= 5) << 1;
      nib |= (u32)(__popc(t9 ^ w1p2) >= 5) << 2;
      nib |= (u32)(__popc(t9 ^ w1p3) >= 5) << 3;
      a1[pix >> 4] |= (u64)nib << ((pix & 15) * 4);
      ++pix;
    }
  }

  // ---- Layer 2: 8ch, 7x7 -> 3x3, 36 taps (ternary out) ----
  u64 v2lo = 0, nz2lo = 0; u32 v2hi = 0, nz2hi = 0;  // bit 8*(3*oy+ox)+d
  #pragma unroll
  for (int oy = 0; oy < 3; ++oy) {
    #pragma unroll
    for (int ox = 0; ox < 3; ++ox) {
      u64 T = 0;
      #pragma unroll
      for (int ky = 0; ky < 3; ++ky) {
        const int p = 4 * (7 * (2 * oy + ky) + 2 * ox);
        const int w = p >> 6, o = p & 63;
        u64 v = a1[w] >> o;
        if (o > 52) v |= a1[w + 1] << (64 - o);
        T |= (v & 0xFFFull) << (12 * ky);
      }
      const int pix2 = 3 * oy + ox;
      u32 bv = 0, bz = 0;
      #pragma unroll
      for (int d = 0; d < 8; ++d) {
        const int cnt = __popcll(T ^ W2[d]);  // #neg products of 36
        bv |= (u32)(cnt > 18) << d;           // sum = 36-2cnt < 0
        bz |= (u32)(cnt != 18) << d;          // nonzero
      }
      if (pix2 < 8) { v2lo |= (u64)bv << (8 * pix2); nz2lo |= (u64)bz << (8 * pix2); }
      else          { v2hi = bv; nz2hi = bz; }
    }
  }

  // ---- Layer 3: 16ch, 3x3 -> 1x1, 72 taps, ternary in/out ----
  const int nztot = __popcll(nz2lo) + __popc(nz2hi);
  u32 s3v = 0, s3nz = 0;
  #pragma unroll
  for (int e = 0; e < 16; ++e) {
    const int cnt = __popcll(nz2lo & (v2lo ^ W3L[e])) + __popc(nz2hi & (v2hi ^ W3H[e]));
    const int s = nztot - 2 * cnt;
    s3v  |= (u32)(s < 0) << e;
    s3nz |= (u32)(s != 0) << e;
  }

  // ---- FC1: 16 -> 8, ternary ----
  const int n3 = __popc(s3nz);
  u32 hv = 0, hz = 0;
  #pragma unroll
  for (int j = 0; j < 8; ++j) {
    const int c2 = __popc(s3nz & (s3v ^ WF1[j]));
    const int s = n3 - 2 * c2;
    hv |= (u32)(s < 0) << j;
    hz |= (u32)(s != 0) << j;
  }

  // ---- FC2: 8 -> 1 (no hardtanh) ----
  const int c3 = __popc(hz & (hv ^ wf2));
  const int sfin = __popc(hz) - 2 * c3;
  out[b0 + lane] = (float)sfin;
}

extern "C" void kernel_launch(void* const* d_in, const int* in_sizes, int n_in,
                              void* d_out, int out_size, void* d_ws, size_t ws_size,
                              hipStream_t stream) {
  const float* x    = (const float*)d_in[0];
  const float* w1   = (const float*)d_in[1];
  const float* w2   = (const float*)d_in[2];
  const float* w3   = (const float*)d_in[3];
  const float* wfc1 = (const float*)d_in[4];
  const float* wfc2 = (const float*)d_in[5];
  float* out = (float*)d_out;
  const int B = in_sizes[0] / 225;  // 131072

  (void)d_ws; (void)ws_size; (void)n_in; (void)out_size;
  binnet<<<B / 64, 64, 0, stream>>>(x, w1, w2, w3, wfc1, wfc2, out);
}